// Round 1
// baseline (200.374 us; speedup 1.0000x reference)
//
#include <hip/hip_runtime.h>
#include <math.h>

#define BATCH 8192
#define DIM 1024
#define DIM4 256          // DIM/4, float4 per 256-thread block row
#define NCLS 1000
#define NPAIRS 499500.0f  // 1000*999/2

// ---------------- reduction helpers (blockDim.x == 256) ----------------

__device__ inline float waveReduceAdd(float x) {
  #pragma unroll
  for (int o = 32; o > 0; o >>= 1) x += __shfl_down(x, o);
  return x;
}

// broadcast block reduce, sm must hold >= 8 floats
__device__ inline float blockReduce1(float x, float* sm) {
  x = waveReduceAdd(x);
  int lane = threadIdx.x & 63, wid = threadIdx.x >> 6;
  __syncthreads();
  if (lane == 0) sm[wid] = x;
  __syncthreads();
  return sm[0] + sm[1] + sm[2] + sm[3];
}

__device__ inline float2 blockReduce2(float x, float y, float* sm) {
  x = waveReduceAdd(x);
  y = waveReduceAdd(y);
  int lane = threadIdx.x & 63, wid = threadIdx.x >> 6;
  __syncthreads();
  if (lane == 0) { sm[wid * 2] = x; sm[wid * 2 + 1] = y; }
  __syncthreads();
  float rx = sm[0] + sm[2] + sm[4] + sm[6];
  float ry = sm[1] + sm[3] + sm[5] + sm[7];
  return make_float2(rx, ry);
}

// ---------------- setup kernels ----------------

__global__ void zero_kernel(int* counts, float* partials) {
  int t = threadIdx.x;  // 1024 threads, 1 block
  if (t < NCLS) counts[t] = 0;
  if (t < 768) partials[t] = 0.0f;
}

__global__ void count_kernel(const int* __restrict__ labels, int* counts) {
  int j = blockIdx.x * 256 + threadIdx.x;
  if (j < BATCH) atomicAdd(&counts[labels[j]], 1);
}

__global__ void scan_kernel(const int* __restrict__ counts, int* offsets, int* cursor) {
  __shared__ int s[1024];
  int t = threadIdx.x;  // 1024 threads, 1 block
  int v = (t < NCLS) ? counts[t] : 0;
  s[t] = v;
  __syncthreads();
  for (int off = 1; off < 1024; off <<= 1) {
    int u = (t >= off) ? s[t - off] : 0;
    __syncthreads();
    s[t] += u;
    __syncthreads();
  }
  if (t < NCLS) {
    int e = s[t] - v;  // exclusive prefix
    offsets[t] = e;
    cursor[t] = e;
  }
}

__global__ void scatter_kernel(const int* __restrict__ labels, int* cursor,
                               int* rows_sorted) {
  int j = blockIdx.x * 256 + threadIdx.x;
  if (j < BATCH) {
    int pos = atomicAdd(&cursor[labels[j]], 1);
    rows_sorted[pos] = j;
  }
}

// ---------------- center update: one block (256 thr) per class ----------------

__global__ void update_centers_kernel(const float* __restrict__ feats,
                                      const float* __restrict__ centers,
                                      const int* __restrict__ counts,
                                      const int* __restrict__ offsets,
                                      const int* __restrict__ rows_sorted,
                                      float* __restrict__ centers_new,
                                      float* __restrict__ sqn) {
  __shared__ float sm[8];
  __shared__ int s_anynz;
  int c = blockIdx.x;
  int tid = threadIdx.x;
  int n = counts[c];
  int off = offsets[c];

  float4 acc = make_float4(0.f, 0.f, 0.f, 0.f);
  for (int t = 0; t < n; ++t) {
    int r = rows_sorted[off + t];
    float4 v = ((const float4*)(feats + (size_t)r * DIM))[tid];
    float ss = v.x * v.x + v.y * v.y + v.z * v.z + v.w * v.w;
    float tot = blockReduce1(ss, sm);
    float inv = 1.0f / fmaxf(sqrtf(tot), 1e-12f);
    acc.x += v.x * inv; acc.y += v.y * inv; acc.z += v.z * inv; acc.w += v.w * inv;
  }

  float invn = 1.0f / fmaxf((float)n, 1.0f);
  float4 mean = make_float4(acc.x * invn, acc.y * invn, acc.z * invn, acc.w * invn);

  float4 cv = ((const float4*)(centers + (size_t)c * DIM))[tid];
  if (tid == 0) s_anynz = 0;
  __syncthreads();
  if (cv.x != 0.f || cv.y != 0.f || cv.z != 0.f || cv.w != 0.f) s_anynz = 1;
  __syncthreads();

  float4 o;
  if (s_anynz) {  // center not all-zero: momentum update
    o = make_float4(0.9f * cv.x + 0.1f * mean.x, 0.9f * cv.y + 0.1f * mean.y,
                    0.9f * cv.z + 0.1f * mean.z, 0.9f * cv.w + 0.1f * mean.w);
  } else {
    o = mean;
  }
  if (n == 0) o = cv;  // no samples: keep old center

  ((float4*)(centers_new + (size_t)c * DIM))[tid] = o;

  float sq = blockReduce1(o.x * o.x + o.y * o.y + o.z * o.z + o.w * o.w, sm);
  if (tid == 0) sqn[c] = sq;
}

// ---------------- intra losses: 4 rows per 256-thread block ----------------

__global__ void intra_kernel(const float* __restrict__ feats,
                             const float* __restrict__ featsa,
                             const float* __restrict__ centers_new,
                             const int* __restrict__ labels,
                             float* __restrict__ partials) {
  __shared__ float sm[8];
  int tid = threadIdx.x;
  float accC = 0.f, accA = 0.f;
  #pragma unroll
  for (int rr = 0; rr < 4; ++rr) {
    int row = blockIdx.x * 4 + rr;
    float4 f = ((const float4*)(feats + (size_t)row * DIM))[tid];
    float4 fa = ((const float4*)(featsa + (size_t)row * DIM))[tid];
    float2 ss = blockReduce2(f.x * f.x + f.y * f.y + f.z * f.z + f.w * f.w,
                             fa.x * fa.x + fa.y * fa.y + fa.z * fa.z + fa.w * fa.w, sm);
    float invf = 1.0f / fmaxf(sqrtf(ss.x), 1e-12f);
    float inva = 1.0f / fmaxf(sqrtf(ss.y), 1e-12f);
    int lab = labels[row];
    float4 cb = ((const float4*)(centers_new + (size_t)lab * DIM))[tid];
    float dcx = f.x * invf - cb.x, dcy = f.y * invf - cb.y;
    float dcz = f.z * invf - cb.z, dcw = f.w * invf - cb.w;
    float dax = fa.x * inva - cb.x, day = fa.y * inva - cb.y;
    float daz = fa.z * inva - cb.z, daw = fa.w * inva - cb.w;
    float2 d2 = blockReduce2(dcx * dcx + dcy * dcy + dcz * dcz + dcw * dcw,
                             dax * dax + day * day + daz * daz + daw * daw, sm);
    if (tid == 0) { accC += sqrtf(d2.x); accA += sqrtf(d2.y); }
  }
  if (tid == 0) {
    int slot = blockIdx.x & 255;
    atomicAdd(&partials[slot], accC);
    atomicAdd(&partials[256 + slot], accA);
  }
}

// ---------------- inter loss: 64x64-tile fp32 Gram, upper triangle ----------------

#define TS 64
#define KT 16

__global__ void inter_kernel(const float* __restrict__ Cn,
                             const float* __restrict__ sq,
                             float* __restrict__ inter_partial) {
  int bi = blockIdx.y, bj = blockIdx.x;
  if (bj < bi) return;  // upper triangle of tiles only

  __shared__ float As[KT][TS + 4];
  __shared__ float Bs[KT][TS + 4];
  __shared__ float smr[8];

  int tid = threadIdx.x;        // 256
  int tx = tid & 15, ty = tid >> 4;
  int i0 = bi * TS, j0 = bj * TS;
  int lr = tid >> 2;            // 0..63: tile row to load
  int lk = (tid & 3) * 4;       // 0,4,8,12: k offset within tile

  float acc[4][4];
  #pragma unroll
  for (int a = 0; a < 4; ++a)
    #pragma unroll
    for (int b = 0; b < 4; ++b) acc[a][b] = 0.f;

  for (int k0 = 0; k0 < DIM; k0 += KT) {
    float4 av = make_float4(0.f, 0.f, 0.f, 0.f);
    float4 bv = make_float4(0.f, 0.f, 0.f, 0.f);
    if (i0 + lr < NCLS) av = *((const float4*)(Cn + (size_t)(i0 + lr) * DIM + k0 + lk));
    if (j0 + lr < NCLS) bv = *((const float4*)(Cn + (size_t)(j0 + lr) * DIM + k0 + lk));
    __syncthreads();
    As[lk + 0][lr] = av.x; As[lk + 1][lr] = av.y;
    As[lk + 2][lr] = av.z; As[lk + 3][lr] = av.w;
    Bs[lk + 0][lr] = bv.x; Bs[lk + 1][lr] = bv.y;
    Bs[lk + 2][lr] = bv.z; Bs[lk + 3][lr] = bv.w;
    __syncthreads();
    #pragma unroll
    for (int k = 0; k < KT; ++k) {
      float a0 = As[k][ty * 4 + 0], a1 = As[k][ty * 4 + 1];
      float a2 = As[k][ty * 4 + 2], a3 = As[k][ty * 4 + 3];
      float b0 = Bs[k][tx * 4 + 0], b1 = Bs[k][tx * 4 + 1];
      float b2 = Bs[k][tx * 4 + 2], b3 = Bs[k][tx * 4 + 3];
      acc[0][0] += a0 * b0; acc[0][1] += a0 * b1; acc[0][2] += a0 * b2; acc[0][3] += a0 * b3;
      acc[1][0] += a1 * b0; acc[1][1] += a1 * b1; acc[1][2] += a1 * b2; acc[1][3] += a1 * b3;
      acc[2][0] += a2 * b0; acc[2][1] += a2 * b1; acc[2][2] += a2 * b2; acc[2][3] += a2 * b3;
      acc[3][0] += a3 * b0; acc[3][1] += a3 * b1; acc[3][2] += a3 * b2; acc[3][3] += a3 * b3;
    }
  }

  float local = 0.f;
  #pragma unroll
  for (int a = 0; a < 4; ++a) {
    int i = i0 + ty * 4 + a;
    if (i >= NCLS) continue;
    float sqi = sq[i];
    #pragma unroll
    for (int b = 0; b < 4; ++b) {
      int j = j0 + tx * 4 + b;
      if (j < NCLS && i < j) {
        float d2 = sqi + sq[j] - 2.0f * acc[a][b];
        float d = sqrtf(fmaxf(d2, 0.0f));
        local += fmaxf(1.0f - d, 0.0f);
      }
    }
  }
  float tot = blockReduce1(local, smr);
  if (tid == 0) atomicAdd(&inter_partial[(bi * 16 + bj) & 255], tot);
}

// ---------------- final combine ----------------

__global__ void final_kernel(const float* __restrict__ partials, float* __restrict__ out) {
  __shared__ float sm[8];
  int t = threadIdx.x;  // 256
  float c = partials[t];
  float a = partials[256 + t];
  float e = partials[512 + t];
  float2 ca = blockReduce2(c, a, sm);
  float es = blockReduce1(e, sm);
  if (t == 0) {
    float intra = (ca.x + ca.y) * (1.0f / (float)BATCH);
    float inter = es / NPAIRS;
    out[0] = intra - 0.5f * inter;  // LAMBDA_INTRA=1.0, LAMBDA_INTER=0.5
  }
}

// ---------------- launch ----------------

extern "C" void kernel_launch(void* const* d_in, const int* in_sizes, int n_in,
                              void* d_out, int out_size, void* d_ws, size_t ws_size,
                              hipStream_t stream) {
  const float* features     = (const float*)d_in[0];
  const float* features_adv = (const float*)d_in[1];
  const float* centers      = (const float*)d_in[2];
  const int*   labels       = (const int*)d_in[3];
  float* out = (float*)d_out;

  // workspace layout (floats): centers_new[1000*1024] | sqn[1000] | partials[768]
  // then ints: counts[1000] | offsets[1000] | cursor[1000] | rows_sorted[8192]
  float* wsf = (float*)d_ws;
  float* centers_new = wsf;
  float* sqn = wsf + (size_t)NCLS * DIM;
  float* partials = sqn + NCLS;             // [0:256) clean, [256:512) adv, [512:768) inter
  int* counts = (int*)(partials + 768);
  int* offsets = counts + NCLS;
  int* cursor = offsets + NCLS;
  int* rows_sorted = cursor + NCLS;

  hipLaunchKernelGGL(zero_kernel, dim3(1), dim3(1024), 0, stream, counts, partials);
  hipLaunchKernelGGL(count_kernel, dim3(BATCH / 256), dim3(256), 0, stream, labels, counts);
  hipLaunchKernelGGL(scan_kernel, dim3(1), dim3(1024), 0, stream, counts, offsets, cursor);
  hipLaunchKernelGGL(scatter_kernel, dim3(BATCH / 256), dim3(256), 0, stream, labels, cursor,
                     rows_sorted);
  hipLaunchKernelGGL(update_centers_kernel, dim3(NCLS), dim3(256), 0, stream, features,
                     centers, counts, offsets, rows_sorted, centers_new, sqn);
  hipLaunchKernelGGL(intra_kernel, dim3(BATCH / 4), dim3(256), 0, stream, features,
                     features_adv, centers_new, labels, partials);
  hipLaunchKernelGGL(inter_kernel, dim3(16, 16), dim3(256), 0, stream, centers_new, sqn,
                     partials + 512);
  hipLaunchKernelGGL(final_kernel, dim3(1), dim3(256), 0, stream, partials, out);
}

// Round 2
// 155.083 us; speedup vs baseline: 1.2920x; 1.2920x over previous
//
#include <hip/hip_runtime.h>
#include <math.h>

#define BATCH 8192
#define DIM 1024
#define NCLS 1000
#define NPAD 1024         // padded class rows for the bf16 center matrix
#define NPAIRS 499500.0f  // 1000*999/2

typedef float  f32x4  __attribute__((ext_vector_type(4)));
typedef short  bf16x8 __attribute__((ext_vector_type(8)));

// ---------------- helpers ----------------

__device__ inline float waveAllReduceAdd(float x) {
  #pragma unroll
  for (int m = 32; m > 0; m >>= 1) x += __shfl_xor(x, m);
  return x;
}

// block (256 thr) reduce, broadcast; sm >= 8 floats
__device__ inline float blockReduce1(float x, float* sm) {
  x = waveAllReduceAdd(x);
  int lane = threadIdx.x & 63, wid = threadIdx.x >> 6;
  __syncthreads();
  if (lane == 0) sm[wid] = x;
  __syncthreads();
  return sm[0] + sm[1] + sm[2] + sm[3];
}

__device__ inline float bf2f(unsigned short u) {
  return __uint_as_float(((unsigned int)u) << 16);
}

__device__ inline unsigned short f2bf(float f) {
  unsigned int u = __float_as_uint(f);
  u += 0x7FFFu + ((u >> 16) & 1u);  // RNE
  return (unsigned short)(u >> 16);
}

// ---------------- setup ----------------

__global__ void zero_kernel(int* counts, float* partials) {
  int t = threadIdx.x;  // 1 block, 1024 thr
  if (t < NCLS) counts[t] = 0;
  if (t < 768) partials[t] = 0.0f;
}

// wave-per-row: inv L2 norm of features rows + label histogram
__global__ void norms_count_kernel(const float* __restrict__ feats,
                                   const int* __restrict__ labels,
                                   float* __restrict__ invn, int* counts) {
  int lane = threadIdx.x & 63;
  int row = blockIdx.x * 4 + (threadIdx.x >> 6);
  const float4* f4 = (const float4*)(feats + (size_t)row * DIM);
  float ss = 0.f;
  #pragma unroll
  for (int i = 0; i < 4; ++i) {
    float4 v = f4[lane + 64 * i];
    ss += v.x * v.x + v.y * v.y + v.z * v.z + v.w * v.w;
  }
  ss = waveAllReduceAdd(ss);
  if (lane == 0) {
    invn[row] = 1.0f / fmaxf(sqrtf(ss), 1e-12f);
    atomicAdd(&counts[labels[row]], 1);
  }
}

__global__ void scan_kernel(const int* __restrict__ counts, int* offsets, int* cursor) {
  __shared__ int s[1024];
  int t = threadIdx.x;  // 1 block, 1024 thr
  int v = (t < NCLS) ? counts[t] : 0;
  s[t] = v;
  __syncthreads();
  for (int off = 1; off < 1024; off <<= 1) {
    int u = (t >= off) ? s[t - off] : 0;
    __syncthreads();
    s[t] += u;
    __syncthreads();
  }
  if (t < NCLS) {
    int e = s[t] - v;
    offsets[t] = e;
    cursor[t] = e;
  }
}

__global__ void scatter_kernel(const int* __restrict__ labels, int* cursor,
                               int* rows_sorted) {
  int j = blockIdx.x * 256 + threadIdx.x;
  if (j < BATCH) {
    int pos = atomicAdd(&cursor[labels[j]], 1);
    rows_sorted[pos] = j;
  }
}

// ---------------- center update: one block per padded class row ----------------

__global__ void update_centers_kernel(const float* __restrict__ feats,
                                      const float* __restrict__ centers,
                                      const int* __restrict__ counts,
                                      const int* __restrict__ offsets,
                                      const int* __restrict__ rows_sorted,
                                      const float* __restrict__ invn,
                                      unsigned short* __restrict__ centers_bf,
                                      float* __restrict__ sqn) {
  __shared__ float sm[8];
  __shared__ int s_anynz;
  int c = blockIdx.x;   // 0..1023
  int tid = threadIdx.x;

  if (c >= NCLS) {  // zero-pad rows so the MFMA kernel can load unguarded
    ushort4 z = make_ushort4(0, 0, 0, 0);
    ((ushort4*)(centers_bf + (size_t)c * DIM))[tid] = z;
    return;
  }

  int n = counts[c];
  int off = offsets[c];

  float4 acc = make_float4(0.f, 0.f, 0.f, 0.f);
  for (int t = 0; t < n; ++t) {
    int r = rows_sorted[off + t];
    float w = invn[r];
    float4 v = ((const float4*)(feats + (size_t)r * DIM))[tid];
    acc.x += v.x * w; acc.y += v.y * w; acc.z += v.z * w; acc.w += v.w * w;
  }

  float invc = 1.0f / fmaxf((float)n, 1.0f);
  float4 mean = make_float4(acc.x * invc, acc.y * invc, acc.z * invc, acc.w * invc);

  float4 cv = ((const float4*)(centers + (size_t)c * DIM))[tid];
  if (tid == 0) s_anynz = 0;
  __syncthreads();
  if (cv.x != 0.f || cv.y != 0.f || cv.z != 0.f || cv.w != 0.f) s_anynz = 1;
  __syncthreads();

  float4 o;
  if (s_anynz) {
    o = make_float4(0.9f * cv.x + 0.1f * mean.x, 0.9f * cv.y + 0.1f * mean.y,
                    0.9f * cv.z + 0.1f * mean.z, 0.9f * cv.w + 0.1f * mean.w);
  } else {
    o = mean;
  }
  if (n == 0) o = cv;

  ushort4 ob = make_ushort4(f2bf(o.x), f2bf(o.y), f2bf(o.z), f2bf(o.w));
  ((ushort4*)(centers_bf + (size_t)c * DIM))[tid] = ob;

  float sq = blockReduce1(o.x * o.x + o.y * o.y + o.z * o.z + o.w * o.w, sm);
  if (tid == 0) sqn[c] = sq;
}

// ---------------- intra: wave-per-row, no barriers ----------------

__global__ void intra_kernel(const float* __restrict__ feats,
                             const float* __restrict__ featsa,
                             const unsigned short* __restrict__ centers_bf,
                             const int* __restrict__ labels,
                             const float* __restrict__ invn,
                             float* __restrict__ partials) {
  int lane = threadIdx.x & 63;
  int row = blockIdx.x * 4 + (threadIdx.x >> 6);
  const float4* f4 = (const float4*)(feats + (size_t)row * DIM);
  const float4* a4 = (const float4*)(featsa + (size_t)row * DIM);
  int lab = labels[row];
  const ushort4* c4 = (const ushort4*)(centers_bf + (size_t)lab * DIM);

  float4 fv[4], av[4];
  ushort4 cv[4];
  float ssa = 0.f;
  #pragma unroll
  for (int i = 0; i < 4; ++i) {
    fv[i] = f4[lane + 64 * i];
    av[i] = a4[lane + 64 * i];
    cv[i] = c4[lane + 64 * i];
    ssa += av[i].x * av[i].x + av[i].y * av[i].y + av[i].z * av[i].z + av[i].w * av[i].w;
  }
  ssa = waveAllReduceAdd(ssa);
  float inva = 1.0f / fmaxf(sqrtf(ssa), 1e-12f);
  float invf = invn[row];

  float d2c = 0.f, d2a = 0.f;
  #pragma unroll
  for (int i = 0; i < 4; ++i) {
    float cx = bf2f(cv[i].x), cy = bf2f(cv[i].y), cz = bf2f(cv[i].z), cw = bf2f(cv[i].w);
    float dx = fv[i].x * invf - cx, dy = fv[i].y * invf - cy;
    float dz = fv[i].z * invf - cz, dw = fv[i].w * invf - cw;
    d2c += dx * dx + dy * dy + dz * dz + dw * dw;
    float ex = av[i].x * inva - cx, ey = av[i].y * inva - cy;
    float ez = av[i].z * inva - cz, ew = av[i].w * inva - cw;
    d2a += ex * ex + ey * ey + ez * ez + ew * ew;
  }
  d2c = waveAllReduceAdd(d2c);
  d2a = waveAllReduceAdd(d2a);
  if (lane == 0) {
    int slot = row & 255;
    atomicAdd(&partials[slot], sqrtf(d2c));
    atomicAdd(&partials[256 + slot], sqrtf(d2a));
  }
}

// ---------------- inter: bf16 MFMA Gram, 64x64 tile per block ----------------
// wave w of 4 computes the 32x32 quadrant (wy=w>>1, wx=w&1) as 2x2 MFMA
// 16x16x32 fragments. A[m=lane&15][k=(lane>>4)*8+j]; C/D: col=lane&15,
// row=(lane>>4)*4+reg (verified layouts).

__global__ void inter_mfma_kernel(const unsigned short* __restrict__ Cbf,
                                  const float* __restrict__ sq,
                                  float* __restrict__ inter_partial) {
  int bi = blockIdx.y, bj = blockIdx.x;
  if (bj < bi) return;  // upper triangle of tiles

  __shared__ float smr[8];
  int tid = threadIdx.x;          // 256
  int w = tid >> 6;
  int wy = w >> 1, wx = w & 1;
  int lane = tid & 63;
  int m = lane & 15;              // matrix index within 16
  int q = lane >> 4;              // k-group 0..3

  int i0 = bi * 64 + wy * 32;     // block-tile row base for this wave
  int j0 = bj * 64 + wx * 32;

  const unsigned short* arow0 = Cbf + (size_t)(i0 + m) * DIM;
  const unsigned short* arow1 = Cbf + (size_t)(i0 + 16 + m) * DIM;
  const unsigned short* brow0 = Cbf + (size_t)(j0 + m) * DIM;
  const unsigned short* brow1 = Cbf + (size_t)(j0 + 16 + m) * DIM;

  f32x4 acc00 = {0.f, 0.f, 0.f, 0.f}, acc01 = acc00, acc10 = acc00, acc11 = acc00;

  #pragma unroll 4
  for (int k0 = 0; k0 < DIM; k0 += 32) {
    int ko = k0 + q * 8;
    bf16x8 a0 = *(const bf16x8*)(arow0 + ko);
    bf16x8 a1 = *(const bf16x8*)(arow1 + ko);
    bf16x8 b0 = *(const bf16x8*)(brow0 + ko);
    bf16x8 b1 = *(const bf16x8*)(brow1 + ko);
    acc00 = __builtin_amdgcn_mfma_f32_16x16x32_bf16(a0, b0, acc00, 0, 0, 0);
    acc01 = __builtin_amdgcn_mfma_f32_16x16x32_bf16(a0, b1, acc01, 0, 0, 0);
    acc10 = __builtin_amdgcn_mfma_f32_16x16x32_bf16(a1, b0, acc10, 0, 0, 0);
    acc11 = __builtin_amdgcn_mfma_f32_16x16x32_bf16(a1, b1, acc11, 0, 0, 0);
  }

  // hinge over the 4 fragments
  float local = 0.f;
  int colA = lane & 15;           // C/D col
  int rbase = (lane >> 4) * 4;    // C/D row base
  #pragma unroll
  for (int si = 0; si < 2; ++si) {
    #pragma unroll
    for (int sj = 0; sj < 2; ++sj) {
      f32x4 a = (si == 0) ? (sj == 0 ? acc00 : acc01) : (sj == 0 ? acc10 : acc11);
      #pragma unroll
      for (int r = 0; r < 4; ++r) {
        int i = i0 + si * 16 + rbase + r;
        int j = j0 + sj * 16 + colA;
        if (j < NCLS && i < j) {
          float d2 = sq[i] + sq[j] - 2.0f * a[r];
          float d = sqrtf(fmaxf(d2, 0.0f));
          local += fmaxf(1.0f - d, 0.0f);
        }
      }
    }
  }
  float tot = blockReduce1(local, smr);
  if (tid == 0) atomicAdd(&inter_partial[(bi * 16 + bj) & 255], tot);
}

// ---------------- final combine ----------------

__global__ void final_kernel(const float* __restrict__ partials, float* __restrict__ out) {
  __shared__ float sm[8];
  int t = threadIdx.x;  // 256
  float c = partials[t] + partials[256 + t];
  float e = partials[512 + t];
  c = blockReduce1(c, sm);
  e = blockReduce1(e, sm);
  if (t == 0) {
    float intra = c * (1.0f / (float)BATCH);
    float inter = e / NPAIRS;
    out[0] = intra - 0.5f * inter;  // LAMBDA_INTRA=1, LAMBDA_INTER=0.5
  }
}

// ---------------- launch ----------------

extern "C" void kernel_launch(void* const* d_in, const int* in_sizes, int n_in,
                              void* d_out, int out_size, void* d_ws, size_t ws_size,
                              hipStream_t stream) {
  const float* features     = (const float*)d_in[0];
  const float* features_adv = (const float*)d_in[1];
  const float* centers      = (const float*)d_in[2];
  const int*   labels       = (const int*)d_in[3];
  float* out = (float*)d_out;

  // ws layout: centers_bf[1024*1024 u16] | sqn[1000 f] | invn[8192 f] |
  //            partials[768 f] | counts/offsets/cursor[1000 i each] | rows_sorted[8192 i]
  unsigned short* centers_bf = (unsigned short*)d_ws;
  float* sqn = (float*)(centers_bf + (size_t)NPAD * DIM);
  float* invn = sqn + NCLS;
  float* partials = invn + BATCH;
  int* counts = (int*)(partials + 768);
  int* offsets = counts + NCLS;
  int* cursor = offsets + NCLS;
  int* rows_sorted = cursor + NCLS;

  hipLaunchKernelGGL(zero_kernel, dim3(1), dim3(1024), 0, stream, counts, partials);
  hipLaunchKernelGGL(norms_count_kernel, dim3(BATCH / 4), dim3(256), 0, stream,
                     features, labels, invn, counts);
  hipLaunchKernelGGL(scan_kernel, dim3(1), dim3(1024), 0, stream, counts, offsets, cursor);
  hipLaunchKernelGGL(scatter_kernel, dim3(BATCH / 256), dim3(256), 0, stream, labels,
                     cursor, rows_sorted);
  hipLaunchKernelGGL(update_centers_kernel, dim3(NPAD), dim3(256), 0, stream, features,
                     centers, counts, offsets, rows_sorted, invn, centers_bf, sqn);
  hipLaunchKernelGGL(intra_kernel, dim3(BATCH / 4), dim3(256), 0, stream, features,
                     features_adv, centers_bf, labels, invn, partials);
  hipLaunchKernelGGL(inter_mfma_kernel, dim3(16, 16), dim3(256), 0, stream, centers_bf,
                     sqn, partials + 512);
  hipLaunchKernelGGL(final_kernel, dim3(1), dim3(256), 0, stream, partials, out);
}